// Round 15
// baseline (340.691 us; speedup 1.0000x reference)
//
#include <hip/hip_runtime.h>
#include <cstdint>
#include <cstddef>

// ---------------------------------------------------------------------------
// TransformerLayer: hidden,k,v = f(x, qw,qb, kw,kb, vw,vb, w1,b1, w2,b2)
// S=4096, D_MODEL=2048, D_INT=512.  bf16 MFMA GEMMs, fp32 accumulate.
// Round 15: all GEMMs (except scores) on the k32 structure -- BK=32, 48 KiB
// LDS, 3-buffer counted vmcnt(4), 2-ahead staging, 2-3 blk/CU.  This is the
// measured-best occupancy x pipeline combination (FF1 r14: ~764 TF).
// ---------------------------------------------------------------------------

typedef __attribute__((ext_vector_type(8))) short short8;   // 8 x bf16 bits
typedef __attribute__((ext_vector_type(4))) float f32x4;    // MFMA accum

typedef __attribute__((address_space(3))) void lds_void;
typedef __attribute__((address_space(1))) void g_void;

#define SEQ    4096
#define DMODEL 2048
#define DINT   512

#define MEMF() asm volatile("" ::: "memory")
#define BARRIER() do { MEMF(); __builtin_amdgcn_s_barrier(); MEMF(); } while (0)
#define VMCNT6() asm volatile("s_waitcnt vmcnt(6)" ::: "memory")
#define VMCNT4() asm volatile("s_waitcnt vmcnt(4)" ::: "memory")
#define VMCNT0() asm volatile("s_waitcnt vmcnt(0)" ::: "memory")
#define LGKM0()  asm volatile("s_waitcnt lgkmcnt(0)" ::: "memory")

// fp32 -> bf16 bits, round-to-nearest-even
__device__ __forceinline__ unsigned short f2bf(float f) {
  union { float f; unsigned int u; } a;
  a.f = f;
  unsigned int u = a.u;
  u += 0x7fffu + ((u >> 16) & 1u);
  return (unsigned short)(u >> 16);
}
__device__ __forceinline__ float bf2f(unsigned short u) {
  union { unsigned int i; float f; } a;
  a.i = ((unsigned int)u) << 16;
  return a.f;
}

// ---------------------------------------------------------------------------
// fused cast: all six fp32 tensors -> bf16 in one launch (region lookup).
// ---------------------------------------------------------------------------
__global__ __launch_bounds__(256) void cast_all_kernel(
    const float* __restrict__ x,  const float* __restrict__ qw,
    const float* __restrict__ kw, const float* __restrict__ vw,
    const float* __restrict__ w1, const float* __restrict__ w2,
    unsigned short* __restrict__ Xb, unsigned short* __restrict__ QKVWb,
    unsigned short* __restrict__ W1b, unsigned short* __restrict__ W2b) {
  const int i = blockIdx.x * 256 + threadIdx.x;
  const float* src; unsigned short* dst; int off;
  if (i < 2097152)      { src = x;  dst = Xb;               off = i; }
  else if (i < 2359296) { src = qw; dst = QKVWb;            off = i - 2097152; }
  else if (i < 2621440) { src = kw; dst = QKVWb + 1048576;  off = i - 2359296; }
  else if (i < 3670016) { src = vw; dst = QKVWb + 2097152;  off = i - 2621440; }
  else if (i < 4718592) { src = w1; dst = W1b;              off = i - 3670016; }
  else                  { src = w2; dst = W2b;              off = i - 4718592; }
  float4 v = ((const float4*)src)[off];
  ushort4 o;
  o.x = f2bf(v.x); o.y = f2bf(v.y); o.z = f2bf(v.z); o.w = f2bf(v.w);
  ((ushort4*)dst)[off] = o;
}

// ===========================================================================
// k32 K-loop building blocks (shared by both GEMM kernels below):
// 128^2 tile, BK=32, 256 thr (4 waves, 64x64/wave).  LDS 48 KiB:
// A[3][128][32] @ 0, B[3][128][32] @ 24576.  3-buffer counted vmcnt(4),
// 2-ahead staging.  Per sub-iter (computes tile t):
//   VMCNT4   outstanding {t:4, t+1:4}; drain oldest 4 = t   (never 0)
//   BARRIER  all waves' tile-t loads landed; tile t-1 LDS reads retired
//   STAGE(t+2 -> buf (t+2)%3)   (t-1's home; reads done since last iter)
//   RD(t) -> frags ; MM(t) x16 ; LGKM0
// Swizzle: 4-slot rotation (col16B-slot ^ (row&3)) on stage-src and read.
// ===========================================================================

#define K32_DECLS \
  const int tid  = threadIdx.x;                                             \
  const int lane = tid & 63;                                                \
  const int wave = tid >> 6;                                                \
  const int wr   = wave >> 1;                                               \
  const int wc   = wave & 1;                                                \
  const int lr   = lane & 15;                                               \
  const int kg   = lane >> 4;                                               \
  const int brow = blockIdx.x * 128;                                        \
  const int bcol = blockIdx.y * 128;                                        \
  const int srow = tid >> 2;                                                \
  const int ssw  = ((tid & 3) * 8) ^ ((srow & 3) << 3);                     \
  const unsigned short* Asrc = A + (size_t)(brow + srow) * K + ssw;         \
  const unsigned short* Bsrc = B + (size_t)(bcol + srow) * K + ssw;         \
  char* lbase = (char*)&lds[0];                                             \
  const int woff = wave * 1024;                                             \
  f32x4 acc[4][4];                                                          \
  _Pragma("unroll") for (int i = 0; i < 4; ++i)                             \
    _Pragma("unroll") for (int j = 0; j < 4; ++j)                           \
      acc[i][j] = (f32x4){0.f, 0.f, 0.f, 0.f};                              \
  auto STAGE = [&](int d, int tl) {                                         \
    _Pragma("unroll") for (int r = 0; r < 2; ++r)                           \
      __builtin_amdgcn_global_load_lds(                                     \
          (const g_void*)(Asrc + (size_t)(r * 64) * K + tl * 32),           \
          (lds_void*)(lbase + d * 8192 + r * 4096 + woff), 16, 0, 0);       \
    _Pragma("unroll") for (int r = 0; r < 2; ++r)                           \
      __builtin_amdgcn_global_load_lds(                                     \
          (const g_void*)(Bsrc + (size_t)(r * 64) * K + tl * 32),           \
          (lds_void*)(lbase + 24576 + d * 8192 + r * 4096 + woff), 16, 0, 0); \
  };                                                                        \
  auto RD = [&](short8* a, short8* b, int d) {                              \
    _Pragma("unroll") for (int mi = 0; mi < 4; ++mi) {                      \
      const int row = wr * 64 + mi * 16 + lr;                               \
      a[mi] = *(const short8*)(lbase + d * 8192 + row * 64 +                \
                               ((kg ^ (row & 3)) << 4));                    \
    }                                                                       \
    _Pragma("unroll") for (int n = 0; n < 4; ++n) {                         \
      const int row = wc * 64 + n * 16 + lr;                                \
      b[n] = *(const short8*)(lbase + 24576 + d * 8192 + row * 64 +         \
                              ((kg ^ (row & 3)) << 4));                     \
    }                                                                       \
  };                                                                        \
  auto MM = [&](short8* a, short8* b) {                                     \
    __builtin_amdgcn_s_setprio(1);                                          \
    _Pragma("unroll") for (int mi = 0; mi < 4; ++mi)                        \
      _Pragma("unroll") for (int n = 0; n < 4; ++n)                         \
        acc[mi][n] = __builtin_amdgcn_mfma_f32_16x16x32_bf16(               \
            a[mi], b[n], acc[mi][n], 0, 0, 0);                              \
    __builtin_amdgcn_s_setprio(0);                                          \
  }

#define K32_LOOP \
  STAGE(0, 0);                                                              \
  STAGE(1, 1);                                                              \
  VMCNT4();                                                                 \
  BARRIER();                                                                \
  short8 aF[4], bF[4];                                                      \
  int cur = 0, stg = 2;                                                     \
  for (int t = 0; t < NT; ++t) {                                            \
    VMCNT4();                                                               \
    BARRIER();                                                              \
    STAGE(stg, (t + 2 < NT) ? t + 2 : NT - 1);                              \
    RD(aF, bF, cur);                                                        \
    MM(aF, bF);                                                             \
    LGKM0();                                                                \
    cur = (cur == 2) ? 0 : cur + 1;                                         \
    stg = (stg == 2) ? 0 : stg + 1;                                         \
  }                                                                         \
  VMCNT0()

// ---------------------------------------------------------------------------
// general k32 GEMM (P-V, FF1, FF2): optional bias / fp32-resid / bf16-resid /
// relu / fp32-out / bf16-out.
// ---------------------------------------------------------------------------
__global__ __launch_bounds__(256, 2)
void gemm_k32_kernel(const unsigned short* __restrict__ A,
                     const unsigned short* __restrict__ B,
                     int M, int N, int K,
                     const float* __restrict__ bias,
                     const float* __restrict__ residF,
                     const unsigned short* __restrict__ residB,
                     int relu,
                     float* __restrict__ outF,
                     unsigned short* __restrict__ outB)
{
  __shared__ __align__(16) unsigned short lds[24576];   // 48 KiB
  K32_DECLS;
  const int NT = K >> 5;
  K32_LOOP;

#pragma unroll
  for (int mi = 0; mi < 4; ++mi) {
#pragma unroll
    for (int ni = 0; ni < 4; ++ni) {
#pragma unroll
      for (int r = 0; r < 4; ++r) {
        const int row = brow + wr * 64 + mi * 16 + kg * 4 + r;
        const int col = bcol + wc * 64 + ni * 16 + lr;
        float v = acc[mi][ni][r];
        if (bias)   v += bias[col];
        if (residF) v += residF[(size_t)row * N + col];
        if (residB) v += bf2f(residB[(size_t)row * N + col]);
        if (relu)   v = fmaxf(v, 0.0f);
        if (outF)   outF[(size_t)row * N + col] = v;
        if (outB)   outB[(size_t)row * N + col] = f2bf(v);
      }
    }
  }
}

// ---------------------------------------------------------------------------
// QKV k32 GEMM: W = [qw;kw;vw], grid (32,24)=768 -> 3 blk/CU.  Segment
// epilogue (block-uniform, boundaries at 512/1024 align with 128-tiles):
//   col <  512 : q -> Qb bf16
//   col < 1024 : k -> outK fp32 + Kb bf16
//   else       : v -> outV fp32 + VTb bf16 (transposed, ushort4 of 4 rows)
// ---------------------------------------------------------------------------
__global__ __launch_bounds__(256, 2)
void gemm_qkv_k32_kernel(const unsigned short* __restrict__ A,
                         const unsigned short* __restrict__ B,
                         int M, int N, int K,
                         const float* __restrict__ qb,
                         const float* __restrict__ kb,
                         const float* __restrict__ vb,
                         float* __restrict__ outK,
                         float* __restrict__ outV,
                         unsigned short* __restrict__ Qb,
                         unsigned short* __restrict__ Kb,
                         unsigned short* __restrict__ VTb)
{
  __shared__ __align__(16) unsigned short lds[24576];   // 48 KiB
  K32_DECLS;
  const int NT = K >> 5;
  K32_LOOP;

#pragma unroll
  for (int mi = 0; mi < 4; ++mi) {
#pragma unroll
    for (int ni = 0; ni < 4; ++ni) {
      const int row0 = brow + wr * 64 + mi * 16 + kg * 4;
      const int col  = bcol + wc * 64 + ni * 16 + lr;
      if (col < 512) {                       // q -> Qb bf16
        const float b = qb[col];
#pragma unroll
        for (int r = 0; r < 4; r++)
          Qb[(size_t)(row0 + r) * 512 + col] = f2bf(acc[mi][ni][r] + b);
      } else if (col < 1024) {               // k -> outK fp32 + Kb bf16
        const int c2 = col - 512;
        const float b = kb[c2];
#pragma unroll
        for (int r = 0; r < 4; r++) {
          const float t = acc[mi][ni][r] + b;
          outK[(size_t)(row0 + r) * 512 + c2] = t;
          Kb[(size_t)(row0 + r) * 512 + c2] = f2bf(t);
        }
      } else {                               // v -> outV fp32 + VTb (transposed)
        const int c2 = col - 1024;
        const float b = vb[c2];
        ushort4 o;
#pragma unroll
        for (int r = 0; r < 4; r++) {
          const float t = acc[mi][ni][r] + b;
          outV[(size_t)(row0 + r) * 2048 + c2] = t;
          ((unsigned short*)&o)[r] = f2bf(t);
        }
        *(ushort4*)(&VTb[(size_t)c2 * 4096 + row0]) = o;
      }
    }
  }
}

// ---------------------------------------------------------------------------
// 256^2 4-phase GEMM (scores, 2-D grid (16,16)).  r13-exact.
// ---------------------------------------------------------------------------
__global__ __launch_bounds__(512, 2)
void gemm256_kernel(const unsigned short* __restrict__ A,
                    const unsigned short* __restrict__ B,
                    int M, int N, int K,
                    float scale, unsigned short* __restrict__ outB)
{
  __shared__ __align__(16) unsigned short lds[2][2][2][128][64];  // 128 KiB

  const int tid  = threadIdx.x;
  const int lane = tid & 63;
  const int wave = tid >> 6;
  const int wm   = wave >> 2;
  const int wn   = wave & 3;
  const int lr   = lane & 15;
  const int kg   = lane >> 4;
  const int brow = blockIdx.x * 256;
  const int bcol = blockIdx.y * 256;

  const int srow = tid >> 3;
  const int ssw  = ((tid & 7) * 8) ^ ((srow & 7) << 3);
  const unsigned short* Asrc = A + (size_t)(brow + srow) * K + ssw;
  const unsigned short* Bsrc = B + (size_t)(bcol + srow) * K + ssw;

  char* lbase = (char*)&lds[0][0][0][0][0];
  const int woff = wave * 1024;

  f32x4 acc[8][4];
#pragma unroll
  for (int i = 0; i < 8; ++i)
#pragma unroll
    for (int j = 0; j < 4; ++j) acc[i][j] = (f32x4){0.f, 0.f, 0.f, 0.f};

  const int NT = K >> 6;

  auto SA = [&](int d, int h, int q, int tl) {
    __builtin_amdgcn_global_load_lds(
        (const g_void*)(Asrc + (size_t)(h * 128 + q * 64) * K + tl * 64),
        (lds_void*)(lbase + d * 32768 + h * 16384 + q * 8192 + woff), 16, 0, 0);
  };
  auto SB = [&](int d, int h, int q, int tl) {
    __builtin_amdgcn_global_load_lds(
        (const g_void*)(Bsrc + (size_t)(h * 128 + q * 64) * K + tl * 64),
        (lds_void*)(lbase + 65536 + d * 32768 + h * 16384 + q * 8192 + woff), 16, 0, 0);
  };

  auto LDA = [&](short8* a, int d, int mh, int ks) {
    const char* reg = lbase + d * 32768 + wm * 16384;
    const int ke = (ks * 32 + kg * 8) ^ ((lr & 7) << 3);
#pragma unroll
    for (int i = 0; i < 4; ++i) {
      const int row = (mh * 4 + i) * 16 + lr;
      a[i] = *(const short8*)(reg + row * 128 + ke * 2);
    }
  };
  auto LDB = [&](short8* b, int d, int ks) {
    const char* reg = lbase + 65536 + d * 32768 + (wn >> 1) * 16384;
    const int ke = (ks * 32 + kg * 8) ^ ((lr & 7) << 3);
#pragma unroll
    for (int n = 0; n < 4; ++n) {
      const int row = (wn & 1) * 64 + n * 16 + lr;
      b[n] = *(const short8*)(reg + row * 128 + ke * 2);
    }
  };

  auto MM = [&](int mh, short8* a, short8* b) {
    __builtin_amdgcn_s_setprio(1);
#pragma unroll
    for (int i = 0; i < 4; ++i)
#pragma unroll
      for (int n = 0; n < 4; ++n)
        acc[mh * 4 + i][n] = __builtin_amdgcn_mfma_f32_16x16x32_bf16(
            a[i], b[n], acc[mh * 4 + i][n], 0, 0, 0);
    __builtin_amdgcn_s_setprio(0);
  };

  SA(0, 0, 0, 0); SA(0, 0, 1, 0); SA(0, 1, 0, 0); SA(0, 1, 1, 0);
  SB(0, 0, 0, 0); SB(0, 0, 1, 0); SB(0, 1, 0, 0); SB(0, 1, 1, 0);
  SB(1, 0, 0, 1); SB(1, 0, 1, 1); SA(1, 0, 0, 1);
  SB(1, 1, 0, 1); SB(1, 1, 1, 1); SA(1, 1, 0, 1);
  VMCNT6();
  BARRIER();

  short8 aT[4], bF0[4], bF1[4];
  for (int t = 0; t < NT; ++t) {
    const int buf = t & 1, nb = buf ^ 1;
    const int t1 = (t + 1 < NT) ? t + 1 : NT - 1;
    const int t2 = (t + 2 < NT) ? t + 2 : NT - 1;

    LDA(aT, buf, 0, 0); LDB(bF0, buf, 0);
    SA(nb, 0, 1, t1); SA(nb, 1, 1, t1);
    BARRIER(); MM(0, aT, bF0); BARRIER();

    LDA(aT, buf, 0, 1); LDB(bF1, buf, 1);
    BARRIER(); MM(0, aT, bF1); BARRIER();

    LDA(aT, buf, 1, 0);
    SB(buf, 0, 0, t2); SB(buf, 0, 1, t2); SA(buf, 0, 0, t2);
    BARRIER(); MM(1, aT, bF0); BARRIER();

    LDA(aT, buf, 1, 1);
    SB(buf, 1, 0, t2); SB(buf, 1, 1, t2); SA(buf, 1, 0, t2);
    BARRIER(); MM(1, aT, bF1);
    VMCNT6();
    BARRIER();
  }
  VMCNT0();

#pragma unroll
  for (int mi = 0; mi < 8; ++mi) {
#pragma unroll
    for (int ni = 0; ni < 4; ++ni) {
#pragma unroll
      for (int r = 0; r < 4; ++r) {
        const int row = brow + wm * 128 + mi * 16 + kg * 4 + r;
        const int col = bcol + wn * 64 + ni * 16 + lr;
        outB[(size_t)row * N + col] = f2bf(acc[mi][ni][r] * scale);
      }
    }
  }
}

// ---------------------------------------------------------------------------
// register-resident row softmax over bf16 scores.
// ---------------------------------------------------------------------------
__global__ __launch_bounds__(256) void softmax_kernel(
    const unsigned short* __restrict__ Scb, unsigned short* __restrict__ P) {
  __shared__ float redm[4];
  __shared__ float reds[4];
  const int tid = threadIdx.x;
  const int row = blockIdx.x;
  const unsigned short* src = Scb + (size_t)row * SEQ;

  short8 h0 = *(const short8*)(src + tid * 8);
  short8 h1 = *(const short8*)(src + tid * 8 + 2048);
  float f[16];
#pragma unroll
  for (int i = 0; i < 8; ++i) f[i]     = bf2f((unsigned short)h0[i]);
#pragma unroll
  for (int i = 0; i < 8; ++i) f[8 + i] = bf2f((unsigned short)h1[i]);

  float lmax = f[0];
#pragma unroll
  for (int i = 1; i < 16; ++i) lmax = fmaxf(lmax, f[i]);
#pragma unroll
  for (int off = 32; off > 0; off >>= 1)
    lmax = fmaxf(lmax, __shfl_xor(lmax, off, 64));
  if ((tid & 63) == 0) redm[tid >> 6] = lmax;
  __syncthreads();
  const float m = fmaxf(fmaxf(redm[0], redm[1]), fmaxf(redm[2], redm[3]));

  float lsum = 0.0f;
#pragma unroll
  for (int i = 0; i < 16; ++i) { f[i] = __expf(f[i] - m); lsum += f[i]; }
#pragma unroll
  for (int off = 32; off > 0; off >>= 1)
    lsum += __shfl_xor(lsum, off, 64);
  if ((tid & 63) == 0) reds[tid >> 6] = lsum;
  __syncthreads();
  const float inv = 1.0f / (reds[0] + reds[1] + reds[2] + reds[3]);

  unsigned short* dst = P + (size_t)row * SEQ;
  short8 o0, o1;
#pragma unroll
  for (int i = 0; i < 8; ++i) o0[i] = (short)f2bf(f[i] * inv);
#pragma unroll
  for (int i = 0; i < 8; ++i) o1[i] = (short)f2bf(f[8 + i] * inv);
  *(short8*)(dst + tid * 8)        = o0;
  *(short8*)(dst + tid * 8 + 2048) = o1;
}

// ---------------------------------------------------------------------------
// launch
// ---------------------------------------------------------------------------
extern "C" void kernel_launch(void* const* d_in, const int* in_sizes, int n_in,
                              void* d_out, int out_size, void* d_ws, size_t ws_size,
                              hipStream_t stream) {
  const float* x  = (const float*)d_in[0];
  const float* qw = (const float*)d_in[1];
  const float* qb = (const float*)d_in[2];
  const float* kw = (const float*)d_in[3];
  const float* kb = (const float*)d_in[4];
  const float* vw = (const float*)d_in[5];
  const float* vb = (const float*)d_in[6];
  const float* w1 = (const float*)d_in[7];
  const float* b1 = (const float*)d_in[8];
  const float* w2 = (const float*)d_in[9];
  const float* b2 = (const float*)d_in[10];
  float* out = (float*)d_out;   // [hidden(8388608) | k(2097152) | v(8388608)]
  char* ws = (char*)d_ws;

  const size_t MB = 1048576;
  unsigned short* Xb    = (unsigned short*)(ws + 0 * MB);    // 16M, dead after QKV
  unsigned short* QKVWb = (unsigned short*)(ws + 16 * MB);   // 12M, dead after QKV
  unsigned short* Pb    = (unsigned short*)(ws + 0 * MB);    // 32M, overlays Xb+QKVWb
  unsigned short* W1b   = (unsigned short*)(ws + 32 * MB);   //  8M
  unsigned short* W2b   = (unsigned short*)(ws + 40 * MB);   //  8M
  unsigned short* Qb    = (unsigned short*)(ws + 48 * MB);   //  4M
  unsigned short* Kb    = (unsigned short*)(ws + 52 * MB);   //  4M
  unsigned short* VTb   = (unsigned short*)(ws + 72 * MB);   // 16M (written by QKV)
  unsigned short* Scb   = (unsigned short*)(ws + 88 * MB);   // 32M, dead after softmax
  unsigned short* X1b   = (unsigned short*)(ws + 120 * MB);  // 16M
  unsigned short* XRb   = (unsigned short*)(ws + 136 * MB);  // 16M

  // one fused cast
  cast_all_kernel<<<22528, 256, 0, stream>>>(
      x, qw, kw, vw, w1, w2, Xb, QKVWb, W1b, W2b);

  // q,k,v = x @ [qw;kw;vw]^T + bias; V^T direct  [k32, 768 blocks, 3/CU]
  gemm_qkv_k32_kernel<<<dim3(32, 24), dim3(256), 0, stream>>>(
      Xb, QKVWb, SEQ, 3072, DMODEL, qb, kb, vb,
      out + 8388608, out + 10485760, Qb, Kb, VTb);
  // scores = (q @ k^T) / sqrt(512)  -> bf16
  gemm256_kernel<<<dim3(16, 16), dim3(512), 0, stream>>>(
      Qb, Kb, SEQ, SEQ, DINT, 0.04419417382415922f, Scb);
  // P = softmax(scores)  -> bf16
  softmax_kernel<<<4096, dim3(256), 0, stream>>>(Scb, Pb);
  // x_residual = P @ V + x  -> bf16   [k32, 512 blocks, 2/CU, NT=128]
  gemm_k32_kernel<<<dim3(32, 16), dim3(256), 0, stream>>>(
      Pb, VTb, SEQ, DMODEL, SEQ, nullptr, x, nullptr, 0, nullptr, XRb);
  // x1 = relu(x_residual @ w1^T + b1)  -> bf16   [k32]
  gemm_k32_kernel<<<dim3(32, 16), dim3(256), 0, stream>>>(
      XRb, W1b, SEQ, DMODEL, DMODEL, b1, nullptr, nullptr, 1, nullptr, X1b);
  // hidden = x1 @ w2^T + b2 + x_residual(bf16)  -> fp32 (out)   [k32]
  gemm_k32_kernel<<<dim3(32, 16), dim3(256), 0, stream>>>(
      X1b, W2b, SEQ, DMODEL, DMODEL, b2, nullptr, XRb, 0, out, nullptr);
}

// Round 16
// 314.307 us; speedup vs baseline: 1.0839x; 1.0839x over previous
//
#include <hip/hip_runtime.h>
#include <cstdint>
#include <cstddef>

// ---------------------------------------------------------------------------
// TransformerLayer: hidden,k,v = f(x, qw,qb, kw,kb, vw,vb, w1,b1, w2,b2)
// S=4096, D_MODEL=2048, D_INT=512.  bf16 MFMA GEMMs, fp32 accumulate.
// Round 16: revert to the r14 measured-best configuration (315.2 us).
// r15's k32 migration regressed (BK=32 geometry has irreducible LDS bank
// conflicts: 8.4e6 vs k3's 0); r14 decomposition re-credited to P-V
// WRITE_SIZE drop + bf16 residual, not the k32 structure.
// Config: QKV 2-phase BK=32 (3 blk/CU) | scores gemm256 | P-V k3 (bf16 out)
//         | FF1 k32 | FF2 k3 (bf16 resid).
// ---------------------------------------------------------------------------

typedef __attribute__((ext_vector_type(8))) short short8;   // 8 x bf16 bits
typedef __attribute__((ext_vector_type(4))) float f32x4;    // MFMA accum

typedef __attribute__((address_space(3))) void lds_void;
typedef __attribute__((address_space(1))) void g_void;

#define SEQ    4096
#define DMODEL 2048
#define DINT   512

#define MEMF() asm volatile("" ::: "memory")
#define BARRIER() do { MEMF(); __builtin_amdgcn_s_barrier(); MEMF(); } while (0)
#define VMCNT12() asm volatile("s_waitcnt vmcnt(12)" ::: "memory")
#define VMCNT6() asm volatile("s_waitcnt vmcnt(6)" ::: "memory")
#define VMCNT4() asm volatile("s_waitcnt vmcnt(4)" ::: "memory")
#define VMCNT0() asm volatile("s_waitcnt vmcnt(0)" ::: "memory")
#define LGKM0()  asm volatile("s_waitcnt lgkmcnt(0)" ::: "memory")

// fp32 -> bf16 bits, round-to-nearest-even
__device__ __forceinline__ unsigned short f2bf(float f) {
  union { float f; unsigned int u; } a;
  a.f = f;
  unsigned int u = a.u;
  u += 0x7fffu + ((u >> 16) & 1u);
  return (unsigned short)(u >> 16);
}
__device__ __forceinline__ float bf2f(unsigned short u) {
  union { unsigned int i; float f; } a;
  a.i = ((unsigned int)u) << 16;
  return a.f;
}

// ---------------------------------------------------------------------------
// fused cast: all six fp32 tensors -> bf16 in one launch (region lookup).
// ---------------------------------------------------------------------------
__global__ __launch_bounds__(256) void cast_all_kernel(
    const float* __restrict__ x,  const float* __restrict__ qw,
    const float* __restrict__ kw, const float* __restrict__ vw,
    const float* __restrict__ w1, const float* __restrict__ w2,
    unsigned short* __restrict__ Xb, unsigned short* __restrict__ QKVWb,
    unsigned short* __restrict__ W1b, unsigned short* __restrict__ W2b) {
  const int i = blockIdx.x * 256 + threadIdx.x;
  const float* src; unsigned short* dst; int off;
  if (i < 2097152)      { src = x;  dst = Xb;               off = i; }
  else if (i < 2359296) { src = qw; dst = QKVWb;            off = i - 2097152; }
  else if (i < 2621440) { src = kw; dst = QKVWb + 1048576;  off = i - 2359296; }
  else if (i < 3670016) { src = vw; dst = QKVWb + 2097152;  off = i - 2621440; }
  else if (i < 4718592) { src = w1; dst = W1b;              off = i - 3670016; }
  else                  { src = w2; dst = W2b;              off = i - 4718592; }
  float4 v = ((const float4*)src)[off];
  ushort4 o;
  o.x = f2bf(v.x); o.y = f2bf(v.y); o.z = f2bf(v.z); o.w = f2bf(v.w);
  ((ushort4*)dst)[off] = o;
}

// ---------------------------------------------------------------------------
// Fused QKV GEMM: 2-phase 128^2, BK=32 double-buffered (32 KiB LDS,
// grid (32,24)=768 -> 3 blk/CU).  V^T written directly.
// ---------------------------------------------------------------------------
__global__ __launch_bounds__(256)
void gemm_qkv_kernel(const unsigned short* __restrict__ A,
                     const unsigned short* __restrict__ W,
                     int M, int N, int K,
                     const float* __restrict__ qb,
                     const float* __restrict__ kb,
                     const float* __restrict__ vb,
                     float* __restrict__ outK,
                     float* __restrict__ outV,
                     unsigned short* __restrict__ Qb,
                     unsigned short* __restrict__ Kb,
                     unsigned short* __restrict__ VTb)
{
  __shared__ __align__(16) unsigned short As[2][128][32];
  __shared__ __align__(16) unsigned short Bs[2][128][32];

  const int tid  = threadIdx.x;
  const int lane = tid & 63;
  const int wave = tid >> 6;
  const int wr   = wave >> 1;
  const int wc   = wave & 1;
  const int brow = blockIdx.x * 128;
  const int bcol = blockIdx.y * 128;
  const int lr   = lane & 15;
  const int kg   = lane >> 4;

  const int srow  = tid >> 2;          // 0..63
  const int scol  = (tid & 3) * 8;
  const int wbase = wave * 16;
  const unsigned short* Ab = A + (size_t)(brow + srow) * K + scol;
  const unsigned short* Bb = W + (size_t)(bcol + srow) * K + scol;

  f32x4 acc[4][4];
#pragma unroll
  for (int i = 0; i < 4; i++)
#pragma unroll
    for (int j = 0; j < 4; j++) acc[i][j] = (f32x4){0.f, 0.f, 0.f, 0.f};

  auto stage = [&](int d, int k0) {
#pragma unroll
    for (int j = 0; j < 2; ++j) {
      __builtin_amdgcn_global_load_lds((const g_void*)(Ab + (size_t)(j * 64) * K + k0),
                                       (lds_void*)&As[d][j * 64 + wbase][0], 16, 0, 0);
      __builtin_amdgcn_global_load_lds((const g_void*)(Bb + (size_t)(j * 64) * K + k0),
                                       (lds_void*)&Bs[d][j * 64 + wbase][0], 16, 0, 0);
    }
  };

  auto compute = [&](int d) {
    short8 aF[4], bF[4];
#pragma unroll
    for (int mi = 0; mi < 4; ++mi)
      aF[mi] = *(const short8*)&As[d][wr * 64 + mi * 16 + lr][kg * 8];
#pragma unroll
    for (int ni = 0; ni < 4; ++ni)
      bF[ni] = *(const short8*)&Bs[d][wc * 64 + ni * 16 + lr][kg * 8];
#pragma unroll
    for (int mi = 0; mi < 4; ++mi)
#pragma unroll
      for (int ni = 0; ni < 4; ++ni)
        acc[mi][ni] = __builtin_amdgcn_mfma_f32_16x16x32_bf16(
            aF[mi], bF[ni], acc[mi][ni], 0, 0, 0);
  };

  stage(0, 0);
  __syncthreads();
  int c = 0;
  const int NT = K >> 5;
  for (int t = 0; t < NT; ++t) {
    if (t + 1 < NT) stage(c ^ 1, (t + 1) << 5);
    compute(c);
    __syncthreads();
    c ^= 1;
  }

#pragma unroll
  for (int mi = 0; mi < 4; mi++) {
#pragma unroll
    for (int ni = 0; ni < 4; ni++) {
      const int row0 = brow + wr * 64 + mi * 16 + kg * 4;
      const int col  = bcol + wc * 64 + ni * 16 + lr;
      if (col < 512) {                       // q -> Qb bf16
        const float b = qb[col];
#pragma unroll
        for (int r = 0; r < 4; r++)
          Qb[(size_t)(row0 + r) * 512 + col] = f2bf(acc[mi][ni][r] + b);
      } else if (col < 1024) {               // k -> outK fp32 + Kb bf16
        const int c2 = col - 512;
        const float b = kb[c2];
#pragma unroll
        for (int r = 0; r < 4; r++) {
          const float t = acc[mi][ni][r] + b;
          outK[(size_t)(row0 + r) * 512 + c2] = t;
          Kb[(size_t)(row0 + r) * 512 + c2] = f2bf(t);
        }
      } else {                               // v -> outV fp32 + VTb (transposed)
        const int c2 = col - 1024;
        const float b = vb[c2];
        ushort4 o;
#pragma unroll
        for (int r = 0; r < 4; r++) {
          const float t = acc[mi][ni][r] + b;
          outV[(size_t)(row0 + r) * 2048 + c2] = t;
          ((unsigned short*)&o)[r] = f2bf(t);
        }
        *(ushort4*)(&VTb[(size_t)c2 * 4096 + row0]) = o;
      }
    }
  }
}

// ---------------------------------------------------------------------------
// 256^2 4-phase GEMM (scores GEMM, 2-D grid (16,16)).
// ---------------------------------------------------------------------------
__global__ __launch_bounds__(512, 2)
void gemm256_kernel(const unsigned short* __restrict__ A,
                    const unsigned short* __restrict__ B,
                    int M, int N, int K,
                    float scale, unsigned short* __restrict__ outB)
{
  __shared__ __align__(16) unsigned short lds[2][2][2][128][64];  // 128 KiB

  const int tid  = threadIdx.x;
  const int lane = tid & 63;
  const int wave = tid >> 6;
  const int wm   = wave >> 2;
  const int wn   = wave & 3;
  const int lr   = lane & 15;
  const int kg   = lane >> 4;
  const int brow = blockIdx.x * 256;
  const int bcol = blockIdx.y * 256;

  const int srow = tid >> 3;
  const int ssw  = ((tid & 7) * 8) ^ ((srow & 7) << 3);
  const unsigned short* Asrc = A + (size_t)(brow + srow) * K + ssw;
  const unsigned short* Bsrc = B + (size_t)(bcol + srow) * K + ssw;

  char* lbase = (char*)&lds[0][0][0][0][0];
  const int woff = wave * 1024;

  f32x4 acc[8][4];
#pragma unroll
  for (int i = 0; i < 8; ++i)
#pragma unroll
    for (int j = 0; j < 4; ++j) acc[i][j] = (f32x4){0.f, 0.f, 0.f, 0.f};

  const int NT = K >> 6;

  auto SA = [&](int d, int h, int q, int tl) {
    __builtin_amdgcn_global_load_lds(
        (const g_void*)(Asrc + (size_t)(h * 128 + q * 64) * K + tl * 64),
        (lds_void*)(lbase + d * 32768 + h * 16384 + q * 8192 + woff), 16, 0, 0);
  };
  auto SB = [&](int d, int h, int q, int tl) {
    __builtin_amdgcn_global_load_lds(
        (const g_void*)(Bsrc + (size_t)(h * 128 + q * 64) * K + tl * 64),
        (lds_void*)(lbase + 65536 + d * 32768 + h * 16384 + q * 8192 + woff), 16, 0, 0);
  };

  auto LDA = [&](short8* a, int d, int mh, int ks) {
    const char* reg = lbase + d * 32768 + wm * 16384;
    const int ke = (ks * 32 + kg * 8) ^ ((lr & 7) << 3);
#pragma unroll
    for (int i = 0; i < 4; ++i) {
      const int row = (mh * 4 + i) * 16 + lr;
      a[i] = *(const short8*)(reg + row * 128 + ke * 2);
    }
  };
  auto LDB = [&](short8* b, int d, int ks) {
    const char* reg = lbase + 65536 + d * 32768 + (wn >> 1) * 16384;
    const int ke = (ks * 32 + kg * 8) ^ ((lr & 7) << 3);
#pragma unroll
    for (int n = 0; n < 4; ++n) {
      const int row = (wn & 1) * 64 + n * 16 + lr;
      b[n] = *(const short8*)(reg + row * 128 + ke * 2);
    }
  };

  auto MM = [&](int mh, short8* a, short8* b) {
    __builtin_amdgcn_s_setprio(1);
#pragma unroll
    for (int i = 0; i < 4; ++i)
#pragma unroll
      for (int n = 0; n < 4; ++n)
        acc[mh * 4 + i][n] = __builtin_amdgcn_mfma_f32_16x16x32_bf16(
            a[i], b[n], acc[mh * 4 + i][n], 0, 0, 0);
    __builtin_amdgcn_s_setprio(0);
  };

  SA(0, 0, 0, 0); SA(0, 0, 1, 0); SA(0, 1, 0, 0); SA(0, 1, 1, 0);
  SB(0, 0, 0, 0); SB(0, 0, 1, 0); SB(0, 1, 0, 0); SB(0, 1, 1, 0);
  SB(1, 0, 0, 1); SB(1, 0, 1, 1); SA(1, 0, 0, 1);
  SB(1, 1, 0, 1); SB(1, 1, 1, 1); SA(1, 1, 0, 1);
  VMCNT6();
  BARRIER();

  short8 aT[4], bF0[4], bF1[4];
  for (int t = 0; t < NT; ++t) {
    const int buf = t & 1, nb = buf ^ 1;
    const int t1 = (t + 1 < NT) ? t + 1 : NT - 1;
    const int t2 = (t + 2 < NT) ? t + 2 : NT - 1;

    LDA(aT, buf, 0, 0); LDB(bF0, buf, 0);
    SA(nb, 0, 1, t1); SA(nb, 1, 1, t1);
    BARRIER(); MM(0, aT, bF0); BARRIER();

    LDA(aT, buf, 0, 1); LDB(bF1, buf, 1);
    BARRIER(); MM(0, aT, bF1); BARRIER();

    LDA(aT, buf, 1, 0);
    SB(buf, 0, 0, t2); SB(buf, 0, 1, t2); SA(buf, 0, 0, t2);
    BARRIER(); MM(1, aT, bF0); BARRIER();

    LDA(aT, buf, 1, 1);
    SB(buf, 1, 0, t2); SB(buf, 1, 1, t2); SA(buf, 1, 0, t2);
    BARRIER(); MM(1, aT, bF1);
    VMCNT6();
    BARRIER();
  }
  VMCNT0();

#pragma unroll
  for (int mi = 0; mi < 8; ++mi) {
#pragma unroll
    for (int ni = 0; ni < 4; ++ni) {
#pragma unroll
      for (int r = 0; r < 4; ++r) {
        const int row = brow + wm * 128 + mi * 16 + kg * 4 + r;
        const int col = bcol + wn * 64 + ni * 16 + lr;
        outB[(size_t)row * N + col] = f2bf(acc[mi][ni][r] * scale);
      }
    }
  }
}

// ---------------------------------------------------------------------------
// 256x128 3-buffer counted-vmcnt GEMM (P-V, FF2).  144 KiB LDS.
// residB: optional bf16 residual (row-major [M,N]).
// ---------------------------------------------------------------------------
__global__ __launch_bounds__(512, 2)
void gemm256x128_k3_kernel(const unsigned short* __restrict__ A,
                           const unsigned short* __restrict__ B,
                           int M, int N, int K,
                           const float* __restrict__ bias,
                           const float* __restrict__ resid,
                           const unsigned short* __restrict__ residB,
                           float scale, int relu,
                           float* __restrict__ outF,
                           unsigned short* __restrict__ outB)
{
  __shared__ __align__(16) unsigned short lds[73728];   // 144 KiB

  const int tid  = threadIdx.x;
  const int lane = tid & 63;
  const int wave = tid >> 6;
  const int wm   = wave >> 1;
  const int wn   = wave & 1;
  const int lr   = lane & 15;
  const int kg   = lane >> 4;
  const int brow = blockIdx.x * 256;
  const int bcol = blockIdx.y * 128;

  const int srow = tid >> 3;
  const int ssw  = ((tid & 7) * 8) ^ ((srow & 7) << 3);
  const unsigned short* Asrc = A + (size_t)(brow + srow) * K + ssw;
  const unsigned short* Bsrc = B + (size_t)(bcol + srow) * K + ssw;

  char* lbase = (char*)&lds[0];
  const int woff = wave * 1024;

  f32x4 acc[4][4];
#pragma unroll
  for (int i = 0; i < 4; ++i)
#pragma unroll
    for (int j = 0; j < 4; ++j) acc[i][j] = (f32x4){0.f, 0.f, 0.f, 0.f};

  const int NT = K >> 6;

  auto STAGE = [&](int d, int tl) {
#pragma unroll
    for (int r = 0; r < 4; ++r)
      __builtin_amdgcn_global_load_lds(
          (const g_void*)(Asrc + (size_t)(r * 64) * K + tl * 64),
          (lds_void*)(lbase + d * 32768 + r * 8192 + woff), 16, 0, 0);
#pragma unroll
    for (int r = 0; r < 2; ++r)
      __builtin_amdgcn_global_load_lds(
          (const g_void*)(Bsrc + (size_t)(r * 64) * K + tl * 64),
          (lds_void*)(lbase + 98304 + d * 16384 + r * 8192 + woff), 16, 0, 0);
  };

  auto RD = [&](short8* a, short8* b, int d) {
#pragma unroll
    for (int ks = 0; ks < 2; ++ks) {
      const int ke = (ks * 32 + kg * 8) ^ ((lr & 7) << 3);
      const char* ra = lbase + d * 32768;
      const char* rb = lbase + 98304 + d * 16384;
#pragma unroll
      for (int mi = 0; mi < 4; ++mi)
        a[ks * 4 + mi] = *(const short8*)(ra + (wm * 64 + mi * 16 + lr) * 128 + ke * 2);
#pragma unroll
      for (int n = 0; n < 4; ++n)
        b[ks * 4 + n] = *(const short8*)(rb + (wn * 64 + n * 16 + lr) * 128 + ke * 2);
    }
  };

  auto MMALL = [&](short8* a, short8* b) {
    __builtin_amdgcn_s_setprio(1);
#pragma unroll
    for (int ks = 0; ks < 2; ++ks)
#pragma unroll
      for (int mi = 0; mi < 4; ++mi)
#pragma unroll
        for (int n = 0; n < 4; ++n)
          acc[mi][n] = __builtin_amdgcn_mfma_f32_16x16x32_bf16(
              a[ks * 4 + mi], b[ks * 4 + n], acc[mi][n], 0, 0, 0);
    __builtin_amdgcn_s_setprio(0);
  };

  STAGE(0, 0);
  STAGE(1, 1);
  STAGE(2, 2);
  VMCNT12();
  BARRIER();
  short8 aE[8], bE[8], aO[8], bO[8];
  RD(aE, bE, 0);
  LGKM0();

  for (int t = 0; t < NT; t += 2) {
    VMCNT6();
    BARRIER();
    STAGE(t % 3, (t + 3 < NT) ? t + 3 : NT - 1);
    RD(aO, bO, (t + 1) % 3);
    MMALL(aE, bE);
    LGKM0();
    VMCNT6();
    BARRIER();
    STAGE((t + 1) % 3, (t + 4 < NT) ? t + 4 : NT - 1);
    RD(aE, bE, (t + 2) % 3);
    MMALL(aO, bO);
    LGKM0();
  }
  VMCNT0();

#pragma unroll
  for (int mi = 0; mi < 4; ++mi) {
#pragma unroll
    for (int ni = 0; ni < 4; ++ni) {
#pragma unroll
      for (int r = 0; r < 4; ++r) {
        const int row = brow + wm * 64 + mi * 16 + kg * 4 + r;
        const int col = bcol + wn * 64 + ni * 16 + lr;
        float v = acc[mi][ni][r] * scale;
        if (bias)   v += bias[col];
        if (resid)  v += resid[(size_t)row * N + col];
        if (residB) v += bf2f(residB[(size_t)row * N + col]);
        if (relu)   v = fmaxf(v, 0.0f);
        if (outF)   outF[(size_t)row * N + col] = v;
        if (outB)   outB[(size_t)row * N + col] = f2bf(v);
      }
    }
  }
}

// ---------------------------------------------------------------------------
// k32 (FF1): 128^2 tile, BK=32, 256 thr, 3-buffer counted-vmcnt(4),
// 2-ahead staging, grid (32,16)=512 -> 2 blk/CU.  LDS 48 KiB.
// ---------------------------------------------------------------------------
__global__ __launch_bounds__(256, 2)
void gemm_k32_kernel(const unsigned short* __restrict__ A,
                     const unsigned short* __restrict__ B,
                     int M, int N, int K,
                     const float* __restrict__ bias, int relu,
                     unsigned short* __restrict__ outB)
{
  __shared__ __align__(16) unsigned short lds[24576];   // 48 KiB

  const int tid  = threadIdx.x;
  const int lane = tid & 63;
  const int wave = tid >> 6;     // 0..3
  const int wr   = wave >> 1;    // 0..1
  const int wc   = wave & 1;     // 0..1
  const int lr   = lane & 15;
  const int kg   = lane >> 4;
  const int brow = blockIdx.x * 128;
  const int bcol = blockIdx.y * 128;

  const int srow = tid >> 2;                              // 0..63
  const int ssw  = ((tid & 3) * 8) ^ ((srow & 3) << 3);   // pre-swizzled col
  const unsigned short* Asrc = A + (size_t)(brow + srow) * K + ssw;
  const unsigned short* Bsrc = B + (size_t)(bcol + srow) * K + ssw;

  char* lbase = (char*)&lds[0];
  const int woff = wave * 1024;

  f32x4 acc[4][4];
#pragma unroll
  for (int i = 0; i < 4; ++i)
#pragma unroll
    for (int j = 0; j < 4; ++j) acc[i][j] = (f32x4){0.f, 0.f, 0.f, 0.f};

  const int NT = K >> 5;   // 64 for K=2048

  auto STAGE = [&](int d, int tl) {
#pragma unroll
    for (int r = 0; r < 2; ++r)
      __builtin_amdgcn_global_load_lds(
          (const g_void*)(Asrc + (size_t)(r * 64) * K + tl * 32),
          (lds_void*)(lbase + d * 8192 + r * 4096 + woff), 16, 0, 0);
#pragma unroll
    for (int r = 0; r < 2; ++r)
      __builtin_amdgcn_global_load_lds(
          (const g_void*)(Bsrc + (size_t)(r * 64) * K + tl * 32),
          (lds_void*)(lbase + 24576 + d * 8192 + r * 4096 + woff), 16, 0, 0);
  };

  auto RD = [&](short8* a, short8* b, int d) {
#pragma unroll
    for (int mi = 0; mi < 4; ++mi) {
      const int row = wr * 64 + mi * 16 + lr;
      a[mi] = *(const short8*)(lbase + d * 8192 + row * 64 + ((kg ^ (row & 3)) << 4));
    }
#pragma unroll
    for (int n = 0; n < 4; ++n) {
      const int row = wc * 64 + n * 16 + lr;
      b[n] = *(const short8*)(lbase + 24576 + d * 8192 + row * 64 + ((kg ^ (row & 3)) << 4));
    }
  };

  auto MM = [&](short8* a, short8* b) {
    __builtin_amdgcn_s_setprio(1);
#pragma unroll
    for (int mi = 0; mi < 4; ++mi)
#pragma unroll
      for (int n = 0; n < 4; ++n)
        acc[mi][n] = __builtin_amdgcn_mfma_f32_16x16x32_bf16(
            a[mi], b[n], acc[mi][n], 0, 0, 0);
    __builtin_amdgcn_s_setprio(0);
  };

  STAGE(0, 0);
  STAGE(1, 1);
  VMCNT4();
  BARRIER();

  short8 aF[4], bF[4];
  int cur = 0, stg = 2;
  for (int t = 0; t < NT; ++t) {
    VMCNT4();
    BARRIER();
    STAGE(stg, (t + 2 < NT) ? t + 2 : NT - 1);
    RD(aF, bF, cur);
    MM(aF, bF);
    LGKM0();
    cur = (cur == 2) ? 0 : cur + 1;
    stg = (stg == 2) ? 0 : stg + 1;
  }
  VMCNT0();

#pragma unroll
  for (int mi = 0; mi < 4; ++mi) {
#pragma unroll
    for (int ni = 0; ni < 4; ++ni) {
#pragma unroll
      for (int r = 0; r < 4; ++r) {
        const int row = brow + wr * 64 + mi * 16 + kg * 4 + r;
        const int col = bcol + wc * 64 + ni * 16 + lr;
        float v = acc[mi][ni][r];
        if (bias) v += bias[col];
        if (relu) v = fmaxf(v, 0.0f);
        outB[(size_t)row * N + col] = f2bf(v);
      }
    }
  }
}

// ---------------------------------------------------------------------------
// register-resident row softmax over bf16 scores.
// ---------------------------------------------------------------------------
__global__ __launch_bounds__(256) void softmax_kernel(
    const unsigned short* __restrict__ Scb, unsigned short* __restrict__ P) {
  __shared__ float redm[4];
  __shared__ float reds[4];
  const int tid = threadIdx.x;
  const int row = blockIdx.x;
  const unsigned short* src = Scb + (size_t)row * SEQ;

  short8 h0 = *(const short8*)(src + tid * 8);
  short8 h1 = *(const short8*)(src + tid * 8 + 2048);
  float f[16];
#pragma unroll
  for (int i = 0; i < 8; ++i) f[i]     = bf2f((unsigned short)h0[i]);
#pragma unroll
  for (int i = 0; i < 8; ++i) f[8 + i] = bf2f((unsigned short)h1[i]);

  float lmax = f[0];
#pragma unroll
  for (int i = 1; i < 16; ++i) lmax = fmaxf(lmax, f[i]);
#pragma unroll
  for (int off = 32; off > 0; off >>= 1)
    lmax = fmaxf(lmax, __shfl_xor(lmax, off, 64));
  if ((tid & 63) == 0) redm[tid >> 6] = lmax;
  __syncthreads();
  const float m = fmaxf(fmaxf(redm[0], redm[1]), fmaxf(redm[2], redm[3]));

  float lsum = 0.0f;
#pragma unroll
  for (int i = 0; i < 16; ++i) { f[i] = __expf(f[i] - m); lsum += f[i]; }
#pragma unroll
  for (int off = 32; off > 0; off >>= 1)
    lsum += __shfl_xor(lsum, off, 64);
  if ((tid & 63) == 0) reds[tid >> 6] = lsum;
  __syncthreads();
  const float inv = 1.0f / (reds[0] + reds[1] + reds[2] + reds[3]);

  unsigned short* dst = P + (size_t)row * SEQ;
  short8 o0, o1;
#pragma unroll
  for (int i = 0; i < 8; ++i) o0[i] = (short)f2bf(f[i] * inv);
#pragma unroll
  for (int i = 0; i < 8; ++i) o1[i] = (short)f2bf(f[8 + i] * inv);
  *(short8*)(dst + tid * 8)        = o0;
  *(short8*)(dst + tid * 8 + 2048) = o1;
}

// ---------------------------------------------------------------------------
// launch
// ---------------------------------------------------------------------------
extern "C" void kernel_launch(void* const* d_in, const int* in_sizes, int n_in,
                              void* d_out, int out_size, void* d_ws, size_t ws_size,
                              hipStream_t stream) {
  const float* x  = (const float*)d_in[0];
  const float* qw = (const float*)d_in[1];
  const float* qb = (const float*)d_in[2];
  const float* kw = (const float*)d_in[3];
  const float* kb = (const float*)d_in[4];
  const float* vw = (const float*)d_in[5];
  const float* vb = (const float*)d_in[6];
  const float* w1 = (const float*)d_in[7];
  const float* b1 = (const float*)d_in[8];
  const float* w2 = (const float*)d_in[9];
  const float* b2 = (const float*)d_in[10];
  float* out = (float*)d_out;   // [hidden(8388608) | k(2097152) | v(8388608)]
  char* ws = (char*)d_ws;

  const size_t MB = 1048576;
  unsigned short* Xb    = (unsigned short*)(ws + 0 * MB);    // 16M, dead after QKV
  unsigned short* QKVWb = (unsigned short*)(ws + 16 * MB);   // 12M, dead after QKV
  unsigned short* Pb    = (unsigned short*)(ws + 0 * MB);    // 32M, overlays Xb+QKVWb
  unsigned short* W1b   = (unsigned short*)(ws + 32 * MB);   //  8M
  unsigned short* W2b   = (unsigned short*)(ws + 40 * MB);   //  8M
  unsigned short* Qb    = (unsigned short*)(ws + 48 * MB);   //  4M
  unsigned short* Kb    = (unsigned short*)(ws + 52 * MB);   //  4M
  unsigned short* VTb   = (unsigned short*)(ws + 72 * MB);   // 16M (written by QKV)
  unsigned short* Scb   = (unsigned short*)(ws + 88 * MB);   // 32M, dead after softmax
  unsigned short* X1b   = (unsigned short*)(ws + 120 * MB);  // 16M
  unsigned short* XRb   = (unsigned short*)(ws + 136 * MB);  // 16M

  // one fused cast
  cast_all_kernel<<<22528, 256, 0, stream>>>(
      x, qw, kw, vw, w1, w2, Xb, QKVWb, W1b, W2b);

  // q,k,v = x @ [qw;kw;vw]^T + bias; V^T written directly (768 blocks, 3/CU)
  gemm_qkv_kernel<<<dim3(32, 24), dim3(256), 0, stream>>>(
      Xb, QKVWb, SEQ, 3072, DMODEL, qb, kb, vb,
      out + 8388608, out + 10485760, Qb, Kb, VTb);
  // scores = (q @ k^T) / sqrt(512)  -> bf16
  gemm256_kernel<<<dim3(16, 16), dim3(512), 0, stream>>>(
      Qb, Kb, SEQ, SEQ, DINT, 0.04419417382415922f, Scb);
  // P = softmax(scores)  -> bf16
  softmax_kernel<<<4096, dim3(256), 0, stream>>>(Scb, Pb);
  // x_residual = P @ V + x  -> bf16 only
  gemm256x128_k3_kernel<<<dim3(16, 16), dim3(512), 0, stream>>>(
      Pb, VTb, SEQ, DMODEL, SEQ, nullptr, x, nullptr, 1.0f, 0, nullptr, XRb);
  // x1 = relu(x_residual @ w1^T + b1)  -> bf16   [k32, 512 blocks]
  gemm_k32_kernel<<<dim3(32, 16), dim3(256), 0, stream>>>(
      XRb, W1b, SEQ, DMODEL, DMODEL, b1, 1, X1b);
  // hidden = x1 @ w2^T + b2 + x_residual(bf16)  -> fp32 (out)  [k3]
  gemm256x128_k3_kernel<<<dim3(16, 16), dim3(512), 0, stream>>>(
      X1b, W2b, SEQ, DMODEL, DMODEL, b2, nullptr, XRb, 1.0f, 0, out, nullptr);
}

// Round 17
// 310.778 us; speedup vs baseline: 1.0962x; 1.0114x over previous
//
#include <hip/hip_runtime.h>
#include <cstdint>
#include <cstddef>

// ---------------------------------------------------------------------------
// TransformerLayer: hidden,k,v = f(x, qw,qb, kw,kb, vw,vb, w1,b1, w2,b2)
// S=4096, D_MODEL=2048, D_INT=512.  bf16 MFMA GEMMs, fp32 accumulate.
// Round 17: single-variable A/B -- FF1 moved from k32 to the proven k3
// kernel (arg change only).  All else identical to r16 (314.3 us best).
// Config: QKV 2-phase BK=32 (3 blk/CU) | scores gemm256 | P-V k3 (bf16 out)
//         | FF1 k3 | FF2 k3 (bf16 resid).
// ---------------------------------------------------------------------------

typedef __attribute__((ext_vector_type(8))) short short8;   // 8 x bf16 bits
typedef __attribute__((ext_vector_type(4))) float f32x4;    // MFMA accum

typedef __attribute__((address_space(3))) void lds_void;
typedef __attribute__((address_space(1))) void g_void;

#define SEQ    4096
#define DMODEL 2048
#define DINT   512

#define MEMF() asm volatile("" ::: "memory")
#define BARRIER() do { MEMF(); __builtin_amdgcn_s_barrier(); MEMF(); } while (0)
#define VMCNT12() asm volatile("s_waitcnt vmcnt(12)" ::: "memory")
#define VMCNT6() asm volatile("s_waitcnt vmcnt(6)" ::: "memory")
#define VMCNT0() asm volatile("s_waitcnt vmcnt(0)" ::: "memory")
#define LGKM0()  asm volatile("s_waitcnt lgkmcnt(0)" ::: "memory")

// fp32 -> bf16 bits, round-to-nearest-even
__device__ __forceinline__ unsigned short f2bf(float f) {
  union { float f; unsigned int u; } a;
  a.f = f;
  unsigned int u = a.u;
  u += 0x7fffu + ((u >> 16) & 1u);
  return (unsigned short)(u >> 16);
}
__device__ __forceinline__ float bf2f(unsigned short u) {
  union { unsigned int i; float f; } a;
  a.i = ((unsigned int)u) << 16;
  return a.f;
}

// ---------------------------------------------------------------------------
// fused cast: all six fp32 tensors -> bf16 in one launch (region lookup).
// ---------------------------------------------------------------------------
__global__ __launch_bounds__(256) void cast_all_kernel(
    const float* __restrict__ x,  const float* __restrict__ qw,
    const float* __restrict__ kw, const float* __restrict__ vw,
    const float* __restrict__ w1, const float* __restrict__ w2,
    unsigned short* __restrict__ Xb, unsigned short* __restrict__ QKVWb,
    unsigned short* __restrict__ W1b, unsigned short* __restrict__ W2b) {
  const int i = blockIdx.x * 256 + threadIdx.x;
  const float* src; unsigned short* dst; int off;
  if (i < 2097152)      { src = x;  dst = Xb;               off = i; }
  else if (i < 2359296) { src = qw; dst = QKVWb;            off = i - 2097152; }
  else if (i < 2621440) { src = kw; dst = QKVWb + 1048576;  off = i - 2359296; }
  else if (i < 3670016) { src = vw; dst = QKVWb + 2097152;  off = i - 2621440; }
  else if (i < 4718592) { src = w1; dst = W1b;              off = i - 3670016; }
  else                  { src = w2; dst = W2b;              off = i - 4718592; }
  float4 v = ((const float4*)src)[off];
  ushort4 o;
  o.x = f2bf(v.x); o.y = f2bf(v.y); o.z = f2bf(v.z); o.w = f2bf(v.w);
  ((ushort4*)dst)[off] = o;
}

// ---------------------------------------------------------------------------
// Fused QKV GEMM: 2-phase 128^2, BK=32 double-buffered (32 KiB LDS,
// grid (32,24)=768 -> 3 blk/CU).  V^T written directly.
// ---------------------------------------------------------------------------
__global__ __launch_bounds__(256)
void gemm_qkv_kernel(const unsigned short* __restrict__ A,
                     const unsigned short* __restrict__ W,
                     int M, int N, int K,
                     const float* __restrict__ qb,
                     const float* __restrict__ kb,
                     const float* __restrict__ vb,
                     float* __restrict__ outK,
                     float* __restrict__ outV,
                     unsigned short* __restrict__ Qb,
                     unsigned short* __restrict__ Kb,
                     unsigned short* __restrict__ VTb)
{
  __shared__ __align__(16) unsigned short As[2][128][32];
  __shared__ __align__(16) unsigned short Bs[2][128][32];

  const int tid  = threadIdx.x;
  const int lane = tid & 63;
  const int wave = tid >> 6;
  const int wr   = wave >> 1;
  const int wc   = wave & 1;
  const int brow = blockIdx.x * 128;
  const int bcol = blockIdx.y * 128;
  const int lr   = lane & 15;
  const int kg   = lane >> 4;

  const int srow  = tid >> 2;          // 0..63
  const int scol  = (tid & 3) * 8;
  const int wbase = wave * 16;
  const unsigned short* Ab = A + (size_t)(brow + srow) * K + scol;
  const unsigned short* Bb = W + (size_t)(bcol + srow) * K + scol;

  f32x4 acc[4][4];
#pragma unroll
  for (int i = 0; i < 4; i++)
#pragma unroll
    for (int j = 0; j < 4; j++) acc[i][j] = (f32x4){0.f, 0.f, 0.f, 0.f};

  auto stage = [&](int d, int k0) {
#pragma unroll
    for (int j = 0; j < 2; ++j) {
      __builtin_amdgcn_global_load_lds((const g_void*)(Ab + (size_t)(j * 64) * K + k0),
                                       (lds_void*)&As[d][j * 64 + wbase][0], 16, 0, 0);
      __builtin_amdgcn_global_load_lds((const g_void*)(Bb + (size_t)(j * 64) * K + k0),
                                       (lds_void*)&Bs[d][j * 64 + wbase][0], 16, 0, 0);
    }
  };

  auto compute = [&](int d) {
    short8 aF[4], bF[4];
#pragma unroll
    for (int mi = 0; mi < 4; ++mi)
      aF[mi] = *(const short8*)&As[d][wr * 64 + mi * 16 + lr][kg * 8];
#pragma unroll
    for (int ni = 0; ni < 4; ++ni)
      bF[ni] = *(const short8*)&Bs[d][wc * 64 + ni * 16 + lr][kg * 8];
#pragma unroll
    for (int mi = 0; mi < 4; ++mi)
#pragma unroll
      for (int ni = 0; ni < 4; ++ni)
        acc[mi][ni] = __builtin_amdgcn_mfma_f32_16x16x32_bf16(
            aF[mi], bF[ni], acc[mi][ni], 0, 0, 0);
  };

  stage(0, 0);
  __syncthreads();
  int c = 0;
  const int NT = K >> 5;
  for (int t = 0; t < NT; ++t) {
    if (t + 1 < NT) stage(c ^ 1, (t + 1) << 5);
    compute(c);
    __syncthreads();
    c ^= 1;
  }

#pragma unroll
  for (int mi = 0; mi < 4; mi++) {
#pragma unroll
    for (int ni = 0; ni < 4; ni++) {
      const int row0 = brow + wr * 64 + mi * 16 + kg * 4;
      const int col  = bcol + wc * 64 + ni * 16 + lr;
      if (col < 512) {                       // q -> Qb bf16
        const float b = qb[col];
#pragma unroll
        for (int r = 0; r < 4; r++)
          Qb[(size_t)(row0 + r) * 512 + col] = f2bf(acc[mi][ni][r] + b);
      } else if (col < 1024) {               // k -> outK fp32 + Kb bf16
        const int c2 = col - 512;
        const float b = kb[c2];
#pragma unroll
        for (int r = 0; r < 4; r++) {
          const float t = acc[mi][ni][r] + b;
          outK[(size_t)(row0 + r) * 512 + c2] = t;
          Kb[(size_t)(row0 + r) * 512 + c2] = f2bf(t);
        }
      } else {                               // v -> outV fp32 + VTb (transposed)
        const int c2 = col - 1024;
        const float b = vb[c2];
        ushort4 o;
#pragma unroll
        for (int r = 0; r < 4; r++) {
          const float t = acc[mi][ni][r] + b;
          outV[(size_t)(row0 + r) * 2048 + c2] = t;
          ((unsigned short*)&o)[r] = f2bf(t);
        }
        *(ushort4*)(&VTb[(size_t)c2 * 4096 + row0]) = o;
      }
    }
  }
}

// ---------------------------------------------------------------------------
// 256^2 4-phase GEMM (scores GEMM, 2-D grid (16,16)).
// ---------------------------------------------------------------------------
__global__ __launch_bounds__(512, 2)
void gemm256_kernel(const unsigned short* __restrict__ A,
                    const unsigned short* __restrict__ B,
                    int M, int N, int K,
                    float scale, unsigned short* __restrict__ outB)
{
  __shared__ __align__(16) unsigned short lds[2][2][2][128][64];  // 128 KiB

  const int tid  = threadIdx.x;
  const int lane = tid & 63;
  const int wave = tid >> 6;
  const int wm   = wave >> 2;
  const int wn   = wave & 3;
  const int lr   = lane & 15;
  const int kg   = lane >> 4;
  const int brow = blockIdx.x * 256;
  const int bcol = blockIdx.y * 256;

  const int srow = tid >> 3;
  const int ssw  = ((tid & 7) * 8) ^ ((srow & 7) << 3);
  const unsigned short* Asrc = A + (size_t)(brow + srow) * K + ssw;
  const unsigned short* Bsrc = B + (size_t)(bcol + srow) * K + ssw;

  char* lbase = (char*)&lds[0][0][0][0][0];
  const int woff = wave * 1024;

  f32x4 acc[8][4];
#pragma unroll
  for (int i = 0; i < 8; ++i)
#pragma unroll
    for (int j = 0; j < 4; ++j) acc[i][j] = (f32x4){0.f, 0.f, 0.f, 0.f};

  const int NT = K >> 6;

  auto SA = [&](int d, int h, int q, int tl) {
    __builtin_amdgcn_global_load_lds(
        (const g_void*)(Asrc + (size_t)(h * 128 + q * 64) * K + tl * 64),
        (lds_void*)(lbase + d * 32768 + h * 16384 + q * 8192 + woff), 16, 0, 0);
  };
  auto SB = [&](int d, int h, int q, int tl) {
    __builtin_amdgcn_global_load_lds(
        (const g_void*)(Bsrc + (size_t)(h * 128 + q * 64) * K + tl * 64),
        (lds_void*)(lbase + 65536 + d * 32768 + h * 16384 + q * 8192 + woff), 16, 0, 0);
  };

  auto LDA = [&](short8* a, int d, int mh, int ks) {
    const char* reg = lbase + d * 32768 + wm * 16384;
    const int ke = (ks * 32 + kg * 8) ^ ((lr & 7) << 3);
#pragma unroll
    for (int i = 0; i < 4; ++i) {
      const int row = (mh * 4 + i) * 16 + lr;
      a[i] = *(const short8*)(reg + row * 128 + ke * 2);
    }
  };
  auto LDB = [&](short8* b, int d, int ks) {
    const char* reg = lbase + 65536 + d * 32768 + (wn >> 1) * 16384;
    const int ke = (ks * 32 + kg * 8) ^ ((lr & 7) << 3);
#pragma unroll
    for (int n = 0; n < 4; ++n) {
      const int row = (wn & 1) * 64 + n * 16 + lr;
      b[n] = *(const short8*)(reg + row * 128 + ke * 2);
    }
  };

  auto MM = [&](int mh, short8* a, short8* b) {
    __builtin_amdgcn_s_setprio(1);
#pragma unroll
    for (int i = 0; i < 4; ++i)
#pragma unroll
      for (int n = 0; n < 4; ++n)
        acc[mh * 4 + i][n] = __builtin_amdgcn_mfma_f32_16x16x32_bf16(
            a[i], b[n], acc[mh * 4 + i][n], 0, 0, 0);
    __builtin_amdgcn_s_setprio(0);
  };

  SA(0, 0, 0, 0); SA(0, 0, 1, 0); SA(0, 1, 0, 0); SA(0, 1, 1, 0);
  SB(0, 0, 0, 0); SB(0, 0, 1, 0); SB(0, 1, 0, 0); SB(0, 1, 1, 0);
  SB(1, 0, 0, 1); SB(1, 0, 1, 1); SA(1, 0, 0, 1);
  SB(1, 1, 0, 1); SB(1, 1, 1, 1); SA(1, 1, 0, 1);
  VMCNT6();
  BARRIER();

  short8 aT[4], bF0[4], bF1[4];
  for (int t = 0; t < NT; ++t) {
    const int buf = t & 1, nb = buf ^ 1;
    const int t1 = (t + 1 < NT) ? t + 1 : NT - 1;
    const int t2 = (t + 2 < NT) ? t + 2 : NT - 1;

    LDA(aT, buf, 0, 0); LDB(bF0, buf, 0);
    SA(nb, 0, 1, t1); SA(nb, 1, 1, t1);
    BARRIER(); MM(0, aT, bF0); BARRIER();

    LDA(aT, buf, 0, 1); LDB(bF1, buf, 1);
    BARRIER(); MM(0, aT, bF1); BARRIER();

    LDA(aT, buf, 1, 0);
    SB(buf, 0, 0, t2); SB(buf, 0, 1, t2); SA(buf, 0, 0, t2);
    BARRIER(); MM(1, aT, bF0); BARRIER();

    LDA(aT, buf, 1, 1);
    SB(buf, 1, 0, t2); SB(buf, 1, 1, t2); SA(buf, 1, 0, t2);
    BARRIER(); MM(1, aT, bF1);
    VMCNT6();
    BARRIER();
  }
  VMCNT0();

#pragma unroll
  for (int mi = 0; mi < 8; ++mi) {
#pragma unroll
    for (int ni = 0; ni < 4; ++ni) {
#pragma unroll
      for (int r = 0; r < 4; ++r) {
        const int row = brow + wm * 128 + mi * 16 + kg * 4 + r;
        const int col = bcol + wn * 64 + ni * 16 + lr;
        outB[(size_t)row * N + col] = f2bf(acc[mi][ni][r] * scale);
      }
    }
  }
}

// ---------------------------------------------------------------------------
// 256x128 3-buffer counted-vmcnt GEMM (P-V, FF1, FF2).  144 KiB LDS.
// residB: optional bf16 residual (row-major [M,N]).
// ---------------------------------------------------------------------------
__global__ __launch_bounds__(512, 2)
void gemm256x128_k3_kernel(const unsigned short* __restrict__ A,
                           const unsigned short* __restrict__ B,
                           int M, int N, int K,
                           const float* __restrict__ bias,
                           const float* __restrict__ resid,
                           const unsigned short* __restrict__ residB,
                           float scale, int relu,
                           float* __restrict__ outF,
                           unsigned short* __restrict__ outB)
{
  __shared__ __align__(16) unsigned short lds[73728];   // 144 KiB

  const int tid  = threadIdx.x;
  const int lane = tid & 63;
  const int wave = tid >> 6;
  const int wm   = wave >> 1;
  const int wn   = wave & 1;
  const int lr   = lane & 15;
  const int kg   = lane >> 4;
  const int brow = blockIdx.x * 256;
  const int bcol = blockIdx.y * 128;

  const int srow = tid >> 3;
  const int ssw  = ((tid & 7) * 8) ^ ((srow & 7) << 3);
  const unsigned short* Asrc = A + (size_t)(brow + srow) * K + ssw;
  const unsigned short* Bsrc = B + (size_t)(bcol + srow) * K + ssw;

  char* lbase = (char*)&lds[0];
  const int woff = wave * 1024;

  f32x4 acc[4][4];
#pragma unroll
  for (int i = 0; i < 4; ++i)
#pragma unroll
    for (int j = 0; j < 4; ++j) acc[i][j] = (f32x4){0.f, 0.f, 0.f, 0.f};

  const int NT = K >> 6;   // even, >= 4 at all call sites (K = 2048 / 4096)

  auto STAGE = [&](int d, int tl) {
#pragma unroll
    for (int r = 0; r < 4; ++r)
      __builtin_amdgcn_global_load_lds(
          (const g_void*)(Asrc + (size_t)(r * 64) * K + tl * 64),
          (lds_void*)(lbase + d * 32768 + r * 8192 + woff), 16, 0, 0);
#pragma unroll
    for (int r = 0; r < 2; ++r)
      __builtin_amdgcn_global_load_lds(
          (const g_void*)(Bsrc + (size_t)(r * 64) * K + tl * 64),
          (lds_void*)(lbase + 98304 + d * 16384 + r * 8192 + woff), 16, 0, 0);
  };

  auto RD = [&](short8* a, short8* b, int d) {
#pragma unroll
    for (int ks = 0; ks < 2; ++ks) {
      const int ke = (ks * 32 + kg * 8) ^ ((lr & 7) << 3);
      const char* ra = lbase + d * 32768;
      const char* rb = lbase + 98304 + d * 16384;
#pragma unroll
      for (int mi = 0; mi < 4; ++mi)
        a[ks * 4 + mi] = *(const short8*)(ra + (wm * 64 + mi * 16 + lr) * 128 + ke * 2);
#pragma unroll
      for (int n = 0; n < 4; ++n)
        b[ks * 4 + n] = *(const short8*)(rb + (wn * 64 + n * 16 + lr) * 128 + ke * 2);
    }
  };

  auto MMALL = [&](short8* a, short8* b) {
    __builtin_amdgcn_s_setprio(1);
#pragma unroll
    for (int ks = 0; ks < 2; ++ks)
#pragma unroll
      for (int mi = 0; mi < 4; ++mi)
#pragma unroll
        for (int n = 0; n < 4; ++n)
          acc[mi][n] = __builtin_amdgcn_mfma_f32_16x16x32_bf16(
              a[ks * 4 + mi], b[ks * 4 + n], acc[mi][n], 0, 0, 0);
    __builtin_amdgcn_s_setprio(0);
  };

  STAGE(0, 0);
  STAGE(1, 1);
  STAGE(2, 2);
  VMCNT12();
  BARRIER();
  short8 aE[8], bE[8], aO[8], bO[8];
  RD(aE, bE, 0);
  LGKM0();

  for (int t = 0; t < NT; t += 2) {
    VMCNT6();
    BARRIER();
    STAGE(t % 3, (t + 3 < NT) ? t + 3 : NT - 1);
    RD(aO, bO, (t + 1) % 3);
    MMALL(aE, bE);
    LGKM0();
    VMCNT6();
    BARRIER();
    STAGE((t + 1) % 3, (t + 4 < NT) ? t + 4 : NT - 1);
    RD(aE, bE, (t + 2) % 3);
    MMALL(aO, bO);
    LGKM0();
  }
  VMCNT0();

#pragma unroll
  for (int mi = 0; mi < 4; ++mi) {
#pragma unroll
    for (int ni = 0; ni < 4; ++ni) {
#pragma unroll
      for (int r = 0; r < 4; ++r) {
        const int row = brow + wm * 64 + mi * 16 + kg * 4 + r;
        const int col = bcol + wn * 64 + ni * 16 + lr;
        float v = acc[mi][ni][r] * scale;
        if (bias)   v += bias[col];
        if (resid)  v += resid[(size_t)row * N + col];
        if (residB) v += bf2f(residB[(size_t)row * N + col]);
        if (relu)   v = fmaxf(v, 0.0f);
        if (outF)   outF[(size_t)row * N + col] = v;
        if (outB)   outB[(size_t)row * N + col] = f2bf(v);
      }
    }
  }
}

// ---------------------------------------------------------------------------
// register-resident row softmax over bf16 scores.
// ---------------------------------------------------------------------------
__global__ __launch_bounds__(256) void softmax_kernel(
    const unsigned short* __restrict__ Scb, unsigned short* __restrict__ P) {
  __shared__ float redm[4];
  __shared__ float reds[4];
  const int tid = threadIdx.x;
  const int row = blockIdx.x;
  const unsigned short* src = Scb + (size_t)row * SEQ;

  short8 h0 = *(const short8*)(src + tid * 8);
  short8 h1 = *(const short8*)(src + tid * 8 + 2048);
  float f[16];
#pragma unroll
  for (int i = 0; i < 8; ++i) f[i]     = bf2f((unsigned short)h0[i]);
#pragma unroll
  for (int i = 0; i < 8; ++i) f[8 + i] = bf2f((unsigned short)h1[i]);

  float lmax = f[0];
#pragma unroll
  for (int i = 1; i < 16; ++i) lmax = fmaxf(lmax, f[i]);
#pragma unroll
  for (int off = 32; off > 0; off >>= 1)
    lmax = fmaxf(lmax, __shfl_xor(lmax, off, 64));
  if ((tid & 63) == 0) redm[tid >> 6] = lmax;
  __syncthreads();
  const float m = fmaxf(fmaxf(redm[0], redm[1]), fmaxf(redm[2], redm[3]));

  float lsum = 0.0f;
#pragma unroll
  for (int i = 0; i < 16; ++i) { f[i] = __expf(f[i] - m); lsum += f[i]; }
#pragma unroll
  for (int off = 32; off > 0; off >>= 1)
    lsum += __shfl_xor(lsum, off, 64);
  if ((tid & 63) == 0) reds[tid >> 6] = lsum;
  __syncthreads();
  const float inv = 1.0f / (reds[0] + reds[1] + reds[2] + reds[3]);

  unsigned short* dst = P + (size_t)row * SEQ;
  short8 o0, o1;
#pragma unroll
  for (int i = 0; i < 8; ++i) o0[i] = (short)f2bf(f[i] * inv);
#pragma unroll
  for (int i = 0; i < 8; ++i) o1[i] = (short)f2bf(f[8 + i] * inv);
  *(short8*)(dst + tid * 8)        = o0;
  *(short8*)(dst + tid * 8 + 2048) = o1;
}

// ---------------------------------------------------------------------------
// launch
// ---------------------------------------------------------------------------
extern "C" void kernel_launch(void* const* d_in, const int* in_sizes, int n_in,
                              void* d_out, int out_size, void* d_ws, size_t ws_size,
                              hipStream_t stream) {
  const float* x  = (const float*)d_in[0];
  const float* qw = (const float*)d_in[1];
  const float* qb = (const float*)d_in[2];
  const float* kw = (const float*)d_in[3];
  const float* kb = (const float*)d_in[4];
  const float* vw = (const float*)d_in[5];
  const float* vb = (const float*)d_in[6];
  const float* w1 = (const float*)d_in[7];
  const float* b1 = (const float*)d_in[8];
  const float* w2 = (const float*)d_in[9];
  const float* b2 = (const float*)d_in[10];
  float* out = (float*)d_out;   // [hidden(8388608) | k(2097152) | v(8388608)]
  char* ws = (char*)d_ws;

  const size_t MB = 1048576;
  unsigned short* Xb    = (unsigned short*)(ws + 0 * MB);    // 16M, dead after QKV
  unsigned short* QKVWb = (unsigned short*)(ws + 16 * MB);   // 12M, dead after QKV
  unsigned short* Pb    = (unsigned short*)(ws + 0 * MB);    // 32M, overlays Xb+QKVWb
  unsigned short* W1b   = (unsigned short*)(ws + 32 * MB);   //  8M
  unsigned short* W2b   = (unsigned short*)(ws + 40 * MB);   //  8M
  unsigned short* Qb    = (unsigned short*)(ws + 48 * MB);   //  4M
  unsigned short* Kb    = (unsigned short*)(ws + 52 * MB);   //  4M
  unsigned short* VTb   = (unsigned short*)(ws + 72 * MB);   // 16M (written by QKV)
  unsigned short* Scb   = (unsigned short*)(ws + 88 * MB);   // 32M, dead after softmax
  unsigned short* X1b   = (unsigned short*)(ws + 120 * MB);  // 16M
  unsigned short* XRb   = (unsigned short*)(ws + 136 * MB);  // 16M

  // one fused cast
  cast_all_kernel<<<22528, 256, 0, stream>>>(
      x, qw, kw, vw, w1, w2, Xb, QKVWb, W1b, W2b);

  // q,k,v = x @ [qw;kw;vw]^T + bias; V^T written directly (768 blocks, 3/CU)
  gemm_qkv_kernel<<<dim3(32, 24), dim3(256), 0, stream>>>(
      Xb, QKVWb, SEQ, 3072, DMODEL, qb, kb, vb,
      out + 8388608, out + 10485760, Qb, Kb, VTb);
  // scores = (q @ k^T) / sqrt(512)  -> bf16
  gemm256_kernel<<<dim3(16, 16), dim3(512), 0, stream>>>(
      Qb, Kb, SEQ, SEQ, DINT, 0.04419417382415922f, Scb);
  // P = softmax(scores)  -> bf16
  softmax_kernel<<<4096, dim3(256), 0, stream>>>(Scb, Pb);
  // x_residual = P @ V + x  -> bf16 only
  gemm256x128_k3_kernel<<<dim3(16, 16), dim3(512), 0, stream>>>(
      Pb, VTb, SEQ, DMODEL, SEQ, nullptr, x, nullptr, 1.0f, 0, nullptr, XRb);
  // x1 = relu(x_residual @ w1^T + b1)  -> bf16   [k3, was k32]
  gemm256x128_k3_kernel<<<dim3(16, 16), dim3(512), 0, stream>>>(
      XRb, W1b, SEQ, DMODEL, DMODEL, b1, nullptr, nullptr, 1.0f, 1, nullptr, X1b);
  // hidden = x1 @ w2^T + b2 + x_residual(bf16)  -> fp32 (out)  [k3]
  gemm256x128_k3_kernel<<<dim3(16, 16), dim3(512), 0, stream>>>(
      X1b, W2b, SEQ, DMODEL, DMODEL, b2, nullptr, XRb, 1.0f, 0, out, nullptr);
}